// Round 18
// baseline (60.173 us; speedup 1.0000x reference)
//
#include <hip/hip_runtime.h>
#include <hip/hip_bf16.h>

#define N_TOK 4096
#define CT 256

typedef __attribute__((ext_vector_type(8))) short bf16x8;
typedef __attribute__((ext_vector_type(16))) float f32x16;

__device__ __forceinline__ unsigned pkbf(float a, float b) {
  float2 t; t.x = a; t.y = b;
  __hip_bfloat162 h = __float22bfloat162_rn(t);
  return *reinterpret_cast<unsigned*>(&h);
}

#if __has_builtin(__builtin_amdgcn_exp2f)
__device__ __forceinline__ float fexp2(float x) { return __builtin_amdgcn_exp2f(x); }
#else
__device__ __forceinline__ float fexp2(float x) { return exp2f(x); }
#endif

// ---------------------------------------------------------------------------
// prep: [0,128) X convert+transpose (thermal/optical), [128,224) weight cvt,
// [224,240) emissivity gate.  (byte-identical to R17)
// ---------------------------------------------------------------------------
__global__ __launch_bounds__(256) void prep_kernel(
    const float* __restrict__ thermal, const float* __restrict__ optical,
    const float* __restrict__ Wq, const float* __restrict__ Wk,
    const float* __restrict__ Wv, const float* __restrict__ Wp,
    const float* __restrict__ em, const float* __restrict__ w1,
    const float* __restrict__ b1, const float* __restrict__ w2,
    const float* __restrict__ b2,
    unsigned short* __restrict__ Xbt, unsigned short* __restrict__ Xbo,
    unsigned short* __restrict__ Wall, float* __restrict__ g)
{
  __shared__ unsigned short tile[64][264];
  const int bx = blockIdx.x, tid = threadIdx.x;
  if (bx < 128) {
    const bool th = (bx < 64);
    const float* X = th ? thermal : optical;
    unsigned short* Xb = th ? Xbt : Xbo;
    const int CIN = th ? 256 : 128;
    const int n0 = (th ? bx : bx - 64) * 64;
    const int nl = tid & 63;
    const int cw = (tid >> 6) * 4;
    for (int c0 = 0; c0 < CIN; c0 += 16) {
      int c = c0 + cw;
      float x0 = X[(size_t)(c + 0) * N_TOK + n0 + nl];
      float x1 = X[(size_t)(c + 1) * N_TOK + n0 + nl];
      float x2 = X[(size_t)(c + 2) * N_TOK + n0 + nl];
      float x3 = X[(size_t)(c + 3) * N_TOK + n0 + nl];
      uint2 w; w.x = pkbf(x0, x1); w.y = pkbf(x2, x3);
      *(uint2*)&tile[nl][c] = w;
    }
    __syncthreads();
    const int n = tid >> 2, q = tid & 3;
    const int cb = q * (CIN / 4);
    for (int j = 0; j < CIN / 4; j += 4)
      *(uint2*)(Xb + (size_t)(n0 + n) * CIN + cb + j) = *(const uint2*)&tile[n][cb + j];
  } else if (bx < 224) {
    int i = (bx - 128) * 2048 + tid * 8;   // 196608 total
    const float* src; int off;
    if (i < 65536)       { src = Wq; off = 0; }
    else if (i < 98304)  { src = Wk; off = 65536; }
    else if (i < 131072) { src = Wv; off = 98304; }
    else                 { src = Wp; off = 131072; }
    float4 f0 = *(const float4*)(src + (i - off));
    float4 f1 = *(const float4*)(src + (i - off) + 4);
    uint4 o;
    o.x = pkbf(f0.x, f0.y); o.y = pkbf(f0.z, f0.w);
    o.z = pkbf(f1.x, f1.y); o.w = pkbf(f1.z, f1.w);
    *(uint4*)(Wall + i) = o;
  } else {
    int n = (bx - 224) * 256 + tid;
    int y = n >> 6, x = n & 63;
    float e[9];
#pragma unroll
    for (int dy = 0; dy < 3; dy++)
#pragma unroll
      for (int dx = 0; dx < 3; dx++) {
        int yy = y + dy - 1, xx = x + dx - 1;
        e[dy * 3 + dx] = (yy >= 0 && yy < 64 && xx >= 0 && xx < 64)
                             ? em[yy * 64 + xx] : 0.f;
      }
    float c1[32];
#pragma unroll
    for (int oc = 0; oc < 32; oc++) {
      float a = b1[oc];
#pragma unroll
      for (int t = 0; t < 9; t++) a = fmaf(e[t], w1[oc * 9 + t], a);
      c1[oc] = fmaxf(a, 0.f);
    }
#pragma unroll
    for (int hh = 0; hh < 8; hh++) {
      float a = b2[hh];
#pragma unroll
      for (int oc = 0; oc < 32; oc++) a = fmaf(c1[oc], w2[hh * 32 + oc], a);
      g[hh * N_TOK + n] = 1.f / (1.f + __expf(-a));
    }
  }
}

// ---------------------------------------------------------------------------
// Shared 32tok x 32out MFMA tile.
// ---------------------------------------------------------------------------
template <int CIN>
__device__ __forceinline__ void gemm_tile(
    const unsigned short* __restrict__ xp, const unsigned short* __restrict__ wp,
    f32x16& accE, f32x16& accO)
{
#pragma unroll
  for (int c = 0; c < CIN; c += 32) {
    bf16x8 a0 = *(const bf16x8*)(xp + c);
    bf16x8 b0 = *(const bf16x8*)(wp + c);
    bf16x8 a1 = *(const bf16x8*)(xp + c + 16);
    bf16x8 b1 = *(const bf16x8*)(wp + c + 16);
    accE = __builtin_amdgcn_mfma_f32_32x32x16_bf16(a0, b0, accE, 0, 0, 0);
    accO = __builtin_amdgcn_mfma_f32_32x32x16_bf16(a1, b1, accO, 0, 0, 0);
  }
}

// ---------------------------------------------------------------------------
// Fused QKV projection (byte-identical to R17). grid (32, 24).
// ---------------------------------------------------------------------------
__global__ __launch_bounds__(256) void qkv_kernel(
    const unsigned short* __restrict__ Xbt, const unsigned short* __restrict__ Xbo,
    const unsigned short* __restrict__ Wall,
    const float* __restrict__ bq, const float* __restrict__ bk,
    const float* __restrict__ bv, const float* __restrict__ g,
    unsigned short* __restrict__ Qh, unsigned short* __restrict__ Kh,
    unsigned short* __restrict__ Vf)
{
  __shared__ float ldsT[4][32][33];
  const int tid = threadIdx.x;
  const int wave = tid >> 6, lane = tid & 63;
  const int l31 = lane & 31, hi = lane >> 5;
  const int y = blockIdx.y;
  const int head = y & 7;
  const int n0 = blockIdx.x * 128 + wave * 32;

  f32x16 accE, accO;
#pragma unroll
  for (int i = 0; i < 16; i++) { accE[i] = 0.f; accO[i] = 0.f; }
  float bo;
  if (y < 8) {
    gemm_tile<256>(Xbt + (size_t)(n0 + l31) * 256 + hi * 8,
                   Wall + (size_t)(head * 32 + l31) * 256 + hi * 8, accE, accO);
    bo = bq[head * 32 + l31];
  } else if (y < 16) {
    gemm_tile<128>(Xbo + (size_t)(n0 + l31) * 128 + hi * 8,
                   Wall + 65536 + (size_t)(head * 32 + l31) * 128 + hi * 8, accE, accO);
    bo = bk[head * 32 + l31];
  } else {
    gemm_tile<128>(Xbo + (size_t)(n0 + l31) * 128 + hi * 8,
                   Wall + 98304 + (size_t)(head * 32 + l31) * 128 + hi * 8, accE, accO);
    bo = bv[head * 32 + l31];
  }
  float val[16];
#pragma unroll
  for (int r = 0; r < 16; r++) val[r] = accE[r] + accO[r] + bo;

  if (y < 8) {
    const float QSC = 0.17677669529663689f * 1.4426950408889634f;
#pragma unroll
    for (int r = 0; r < 16; r++) {
      int t = n0 + (r & 3) + 8 * (r >> 2) + 4 * hi;
      val[r] *= QSC * g[head * N_TOK + t];
    }
  }
#pragma unroll
  for (int r = 0; r < 16; r++)
    ldsT[wave][(r & 3) + 8 * (r >> 2) + 4 * hi][l31] = val[r];

  if (y < 16) {
    unsigned pk[8];
#pragma unroll
    for (int i = 0; i < 8; i++)
      pk[i] = pkbf(ldsT[wave][l31][16 * hi + 2 * i],
                   ldsT[wave][l31][16 * hi + 2 * i + 1]);
    unsigned short* dst = (y < 8 ? Qh : Kh) +
        ((size_t)head * N_TOK + n0 + l31) * 32 + 16 * hi;
    *(uint4*)dst = make_uint4(pk[0], pk[1], pk[2], pk[3]);
    *(uint4*)(dst + 8) = make_uint4(pk[4], pk[5], pk[6], pk[7]);
  } else {
    unsigned pk[8];
#pragma unroll
    for (int i = 0; i < 8; i++)
      pk[i] = pkbf(ldsT[wave][16 * hi + 2 * i][l31],
                   ldsT[wave][16 * hi + 2 * i + 1][l31]);
    unsigned short* dst = Vf +
        (((size_t)head * 256 + (n0 >> 4) + hi) * 32 + l31) * 16;
    *(uint4*)dst = make_uint4(pk[0], pk[1], pk[2], pk[3]);
    *(uint4*)(dst + 8) = make_uint4(pk[4], pk[5], pk[6], pk[7]);
  }
}

// ---------------------------------------------------------------------------
// Flash attention (R17 structure: dual-q-group K/V sharing, XCD-pinned heads,
// in-block K-split, setprio, bf16 Ab) + 2-DEEP register prefetch ring —
// hides the ~200cyc L2 load-return latency that the 1-deep ring exposed
// (8 loads/iter vs ~400cyc compute chain, only 2 waves/SIMD of cover).
// ---------------------------------------------------------------------------
__global__ __launch_bounds__(256, 2) void attn_kernel(
    const unsigned short* __restrict__ Qh, const unsigned short* __restrict__ Kh,
    const unsigned short* __restrict__ Vf, unsigned short* __restrict__ Ab)
{
  __shared__ float combA[4][32][33];
  __shared__ float combL[4][32];
  const int tid = threadIdx.x;
  const int wave = tid >> 6, lane = tid & 63;
  const int l31 = lane & 31, hi = lane >> 5;
  const int hh = blockIdx.x & 7;          // XCD-pinned head
  const int qb = blockIdx.x >> 3;         // 0..63
  const int qrow0 = qb * 64;              // group A; group B = +32
  const int kbase0 = wave * 1024;

  const unsigned short* qrowA = Qh + ((size_t)hh * N_TOK + qrow0 + l31) * 32;
  const bf16x8 qfA0 = *(const bf16x8*)(qrowA + hi * 8);
  const bf16x8 qfA1 = *(const bf16x8*)(qrowA + 16 + hi * 8);
  const unsigned short* qrowB = qrowA + 32 * 32;
  const bf16x8 qfB0 = *(const bf16x8*)(qrowB + hi * 8);
  const bf16x8 qfB1 = *(const bf16x8*)(qrowB + 16 + hi * 8);

  const unsigned short* kb_base = Kh + (size_t)hh * (N_TOK * 32);
  const unsigned short* vf_base = Vf + (size_t)hh * (256 * 32 * 16);

  f32x16 accA, accB, zero16;
#pragma unroll
  for (int i = 0; i < 16; i++) { accA[i] = 0.f; accB[i] = 0.f; zero16[i] = 0.f; }
  float lsumA = 0.f, lsumB = 0.f;

#define LK(kb, s) (*(const bf16x8*)(kb_base + (size_t)((kb) + l31) * 32 + (s) * 16 + hi * 8))
#define LV(kt2)   (*(const bf16x8*)(vf_base + (size_t)((kt2) * 32 + l31) * 16 + hi * 8))

  // 2-deep prefetch ring: cur = tile t, nx1 = t+1, nx2 = t+2 (issued at top).
  bf16x8 ckf0 = LK(kbase0, 0),        ckf1 = LK(kbase0, 1);
  bf16x8 cvb0 = LV(kbase0 >> 4),      cvb1 = LV((kbase0 >> 4) + 1);
  bf16x8 nkf0 = LK(kbase0 + 32, 0),   nkf1 = LK(kbase0 + 32, 1);
  bf16x8 nvb0 = LV((kbase0 + 32) >> 4), nvb1 = LV(((kbase0 + 32) >> 4) + 1);

#pragma unroll 2
  for (int kt = 0; kt < 1024; kt += 32) {
    const int far = (kt + 64 < 1024) ? (kbase0 + kt + 64) : kbase0;
    bf16x8 fk0 = LK(far, 0), fk1 = LK(far, 1);
    bf16x8 fv0 = LV(far >> 4), fv1 = LV((far >> 4) + 1);

    __builtin_amdgcn_s_setprio(1);
    f32x16 sA = __builtin_amdgcn_mfma_f32_32x32x16_bf16(ckf0, qfA0, zero16, 0, 0, 0);
    sA = __builtin_amdgcn_mfma_f32_32x32x16_bf16(ckf1, qfA1, sA, 0, 0, 0);
    f32x16 sB = __builtin_amdgcn_mfma_f32_32x32x16_bf16(ckf0, qfB0, zero16, 0, 0, 0);
    sB = __builtin_amdgcn_mfma_f32_32x32x16_bf16(ckf1, qfB1, sB, 0, 0, 0);
    __builtin_amdgcn_s_setprio(0);

    float pA[16], pB[16];
#pragma unroll
    for (int r = 0; r < 16; r++) pA[r] = fexp2(sA[r]);
#pragma unroll
    for (int r = 0; r < 16; r++) pB[r] = fexp2(sB[r]);

    lsumA += (((pA[0] + pA[1]) + (pA[2] + pA[3])) + ((pA[4] + pA[5]) + (pA[6] + pA[7]))) +
             (((pA[8] + pA[9]) + (pA[10] + pA[11])) + ((pA[12] + pA[13]) + (pA[14] + pA[15])));
    lsumB += (((pB[0] + pB[1]) + (pB[2] + pB[3])) + ((pB[4] + pB[5]) + (pB[6] + pB[7]))) +
             (((pB[8] + pB[9]) + (pB[10] + pB[11])) + ((pB[12] + pB[13]) + (pB[14] + pB[15])));

    unsigned aA0 = pkbf(pA[0], pA[1]),   aA1 = pkbf(pA[2], pA[3]);
    unsigned bA0 = pkbf(pA[4], pA[5]),   bA1 = pkbf(pA[6], pA[7]);
    unsigned cA0 = pkbf(pA[8], pA[9]),   cA1 = pkbf(pA[10], pA[11]);
    unsigned dA0 = pkbf(pA[12], pA[13]), dA1 = pkbf(pA[14], pA[15]);
    asm("v_permlane32_swap_b32 %0, %1" : "+v"(aA0), "+v"(bA0));
    asm("v_permlane32_swap_b32 %0, %1" : "+v"(aA1), "+v"(bA1));
    asm("v_permlane32_swap_b32 %0, %1" : "+v"(cA0), "+v"(dA0));
    asm("v_permlane32_swap_b32 %0, %1" : "+v"(cA1), "+v"(dA1));
    unsigned aB0 = pkbf(pB[0], pB[1]),   aB1 = pkbf(pB[2], pB[3]);
    unsigned bB0 = pkbf(pB[4], pB[5]),   bB1 = pkbf(pB[6], pB[7]);
    unsigned cB0 = pkbf(pB[8], pB[9]),   cB1 = pkbf(pB[10], pB[11]);
    unsigned dB0 = pkbf(pB[12], pB[13]), dB1 = pkbf(pB[14], pB[15]);
    asm("v_permlane32_swap_b32 %0, %1" : "+v"(aB0), "+v"(bB0));
    asm("v_permlane32_swap_b32 %0, %1" : "+v"(aB1), "+v"(bB1));
    asm("v_permlane32_swap_b32 %0, %1" : "+v"(cB0), "+v"(dB0));
    asm("v_permlane32_swap_b32 %0, %1" : "+v"(cB1), "+v"(dB1));
    union { unsigned w[4]; bf16x8 v; } uA0, uA1, uB0, uB1;
    uA0.w[0] = aA0; uA0.w[1] = aA1; uA0.w[2] = bA0; uA0.w[3] = bA1;
    uA1.w[0] = cA0; uA1.w[1] = cA1; uA1.w[2] = dA0; uA1.w[3] = dA1;
    uB0.w[0] = aB0; uB0.w[1] = aB1; uB0.w[2] = bB0; uB0.w[3] = bB1;
    uB1.w[0] = cB0; uB1.w[1] = cB1; uB1.w[2] = dB0; uB1.w[3] = dB1;

    __builtin_amdgcn_s_setprio(1);
    accA = __builtin_amdgcn_mfma_f32_32x32x16_bf16(uA0.v, cvb0, accA, 0, 0, 0);
    accA = __builtin_amdgcn_mfma_f32_32x32x16_bf16(uA1.v, cvb1, accA, 0, 0, 0);
    accB = __builtin_amdgcn_mfma_f32_32x32x16_bf16(uB0.v, cvb0, accB, 0, 0, 0);
    accB = __builtin_amdgcn_mfma_f32_32x32x16_bf16(uB1.v, cvb1, accB, 0, 0, 0);
    __builtin_amdgcn_s_setprio(0);

    ckf0 = nkf0; ckf1 = nkf1; cvb0 = nvb0; cvb1 = nvb1;
    nkf0 = fk0;  nkf1 = fk1;  nvb0 = fv0;  nvb1 = fv1;
  }
#undef LK
#undef LV

  const int t = tid >> 3;                  // token 0..31
  const int c4 = (tid & 7) * 4;            // vch group

  // ---- group A combine ----
  float ltA = lsumA + __shfl_xor(lsumA, 32);
  if (hi == 0) combL[wave][l31] = ltA;
#pragma unroll
  for (int r = 0; r < 16; r++)
    combA[wave][(r & 3) + 8 * (r >> 2) + 4 * hi][l31] = accA[r];
  __syncthreads();
  {
    float l = combL[0][t] + combL[1][t] + combL[2][t] + combL[3][t];
    float inv = 1.f / l;
    float o[4];
#pragma unroll
    for (int j = 0; j < 4; j++)
      o[j] = combA[0][t][c4 + j] + combA[1][t][c4 + j] +
             combA[2][t][c4 + j] + combA[3][t][c4 + j];
    uint2 pk;
    pk.x = pkbf(o[0] * inv, o[1] * inv);
    pk.y = pkbf(o[2] * inv, o[3] * inv);
    *(uint2*)(Ab + (size_t)(qrow0 + t) * CT + hh * 32 + c4) = pk;
  }
  __syncthreads();

  // ---- group B combine ----
  float ltB = lsumB + __shfl_xor(lsumB, 32);
  if (hi == 0) combL[wave][l31] = ltB;
#pragma unroll
  for (int r = 0; r < 16; r++)
    combA[wave][(r & 3) + 8 * (r >> 2) + 4 * hi][l31] = accB[r];
  __syncthreads();
  {
    float l = combL[0][t] + combL[1][t] + combL[2][t] + combL[3][t];
    float inv = 1.f / l;
    float o[4];
#pragma unroll
    for (int j = 0; j < 4; j++)
      o[j] = combA[0][t][c4 + j] + combA[1][t][c4 + j] +
             combA[2][t][c4 + j] + combA[3][t][c4 + j];
    uint2 pk;
    pk.x = pkbf(o[0] * inv, o[1] * inv);
    pk.y = pkbf(o[2] * inv, o[3] * inv);
    *(uint2*)(Ab + (size_t)(qrow0 + 32 + t) * CT + hh * 32 + c4) = pk;
  }
}

// ---------------------------------------------------------------------------
// Output projection, 4-wave CIN-split (byte-identical to R17). grid (128, 8).
// ---------------------------------------------------------------------------
__global__ __launch_bounds__(256, 4) void pout_kernel(
    const unsigned short* __restrict__ Ab, const unsigned short* __restrict__ Wall,
    const float* __restrict__ bp, float* __restrict__ out)
{
  __shared__ float comb[4][32][33];
  const int tid = threadIdx.x;
  const int wave = tid >> 6, lane = tid & 63;
  const int l31 = lane & 31, hi = lane >> 5;
  const int n0 = blockIdx.x * 32;
  const int o0 = blockIdx.y * 32;
  const int cbase = wave * 64;

  const unsigned short* xp = Ab + (size_t)(n0 + l31) * 256 + cbase + hi * 8;
  const unsigned short* wp = Wall + 131072 + (size_t)(o0 + l31) * 256 + cbase + hi * 8;

  f32x16 accE, accO;
#pragma unroll
  for (int i = 0; i < 16; i++) { accE[i] = 0.f; accO[i] = 0.f; }
#pragma unroll
  for (int c = 0; c < 64; c += 32) {
    bf16x8 a0 = *(const bf16x8*)(xp + c);
    bf16x8 b0 = *(const bf16x8*)(wp + c);
    bf16x8 a1 = *(const bf16x8*)(xp + c + 16);
    bf16x8 b1 = *(const bf16x8*)(wp + c + 16);
    accE = __builtin_amdgcn_mfma_f32_32x32x16_bf16(a0, b0, accE, 0, 0, 0);
    accO = __builtin_amdgcn_mfma_f32_32x32x16_bf16(a1, b1, accO, 0, 0, 0);
  }
#pragma unroll
  for (int r = 0; r < 16; r++)
    comb[wave][(r & 3) + 8 * (r >> 2) + 4 * hi][l31] = accE[r] + accO[r];
  __syncthreads();

  const int oc = tid >> 3;                 // 0..31
  const int t4 = (tid & 7) * 4;            // 0..28
  const float bo = bp[o0 + oc];
  float4 w;
  w.x = comb[0][t4 + 0][oc] + comb[1][t4 + 0][oc] + comb[2][t4 + 0][oc] + comb[3][t4 + 0][oc] + bo;
  w.y = comb[0][t4 + 1][oc] + comb[1][t4 + 1][oc] + comb[2][t4 + 1][oc] + comb[3][t4 + 1][oc] + bo;
  w.z = comb[0][t4 + 2][oc] + comb[1][t4 + 2][oc] + comb[2][t4 + 2][oc] + comb[3][t4 + 2][oc] + bo;
  w.w = comb[0][t4 + 3][oc] + comb[1][t4 + 3][oc] + comb[2][t4 + 3][oc] + comb[3][t4 + 3][oc] + bo;
  *(float4*)(out + (size_t)(o0 + oc) * N_TOK + n0 + t4) = w;
}

// ---------------------------------------------------------------------------
extern "C" void kernel_launch(void* const* d_in, const int* in_sizes, int n_in,
                              void* d_out, int out_size, void* d_ws, size_t ws_size,
                              hipStream_t stream)
{
  const float* thermal = (const float*)d_in[0];
  const float* optical = (const float*)d_in[1];
  const float* em      = (const float*)d_in[2];
  const float* Wq = (const float*)d_in[3];
  const float* bq = (const float*)d_in[4];
  const float* Wk = (const float*)d_in[5];
  const float* bk = (const float*)d_in[6];
  const float* Wv = (const float*)d_in[7];
  const float* bv = (const float*)d_in[8];
  const float* w1 = (const float*)d_in[9];
  const float* b1 = (const float*)d_in[10];
  const float* w2 = (const float*)d_in[11];
  const float* b2 = (const float*)d_in[12];
  const float* Wp = (const float*)d_in[13];
  const float* bp = (const float*)d_in[14];

  char* ws = (char*)d_ws;
  const size_t MB = 1u << 20;
  unsigned short* Xbt = (unsigned short*)(ws);                  // 2MB
  unsigned short* Xbo = (unsigned short*)(ws + 2 * MB);         // 1MB
  unsigned short* Wall = (unsigned short*)(ws + 3 * MB);        // 384KB
  float* gbuf = (float*)(ws + 3 * MB + 512 * 1024);             // 128KB
  unsigned short* Qh = (unsigned short*)(ws + 4 * MB);          // 2MB
  unsigned short* Kh = (unsigned short*)(ws + 6 * MB);          // 2MB
  unsigned short* Vf = (unsigned short*)(ws + 8 * MB);          // 2MB
  unsigned short* Ab = (unsigned short*)(ws + 10 * MB);         // 2MB

  prep_kernel<<<240, 256, 0, stream>>>(thermal, optical, Wq, Wk, Wv, Wp,
                                       em, w1, b1, w2, b2, Xbt, Xbo, Wall, gbuf);
  qkv_kernel<<<dim3(32, 24), 256, 0, stream>>>(Xbt, Xbo, Wall, bq, bk, bv, gbuf,
                                               Qh, Kh, Vf);
  attn_kernel<<<512, 256, 0, stream>>>(Qh, Kh, Vf, Ab);
  pout_kernel<<<dim3(128, 8), 256, 0, stream>>>(Ab, Wall, bp, (float*)d_out);
}

// Round 19
// 58.132 us; speedup vs baseline: 1.0351x; 1.0351x over previous
//
#include <hip/hip_runtime.h>
#include <hip/hip_bf16.h>

#define N_TOK 4096
#define CT 256

typedef __attribute__((ext_vector_type(8))) short bf16x8;
typedef __attribute__((ext_vector_type(16))) float f32x16;

__device__ __forceinline__ unsigned pkbf(float a, float b) {
  float2 t; t.x = a; t.y = b;
  __hip_bfloat162 h = __float22bfloat162_rn(t);
  return *reinterpret_cast<unsigned*>(&h);
}

#if __has_builtin(__builtin_amdgcn_exp2f)
__device__ __forceinline__ float fexp2(float x) { return __builtin_amdgcn_exp2f(x); }
#else
__device__ __forceinline__ float fexp2(float x) { return exp2f(x); }
#endif

// ---------------------------------------------------------------------------
// prep: [0,128) X convert+transpose (thermal/optical), [128,224) weight cvt,
// [224,240) emissivity gate.
// ---------------------------------------------------------------------------
__global__ __launch_bounds__(256) void prep_kernel(
    const float* __restrict__ thermal, const float* __restrict__ optical,
    const float* __restrict__ Wq, const float* __restrict__ Wk,
    const float* __restrict__ Wv, const float* __restrict__ Wp,
    const float* __restrict__ em, const float* __restrict__ w1,
    const float* __restrict__ b1, const float* __restrict__ w2,
    const float* __restrict__ b2,
    unsigned short* __restrict__ Xbt, unsigned short* __restrict__ Xbo,
    unsigned short* __restrict__ Wall, float* __restrict__ g)
{
  __shared__ unsigned short tile[64][264];
  const int bx = blockIdx.x, tid = threadIdx.x;
  if (bx < 128) {
    const bool th = (bx < 64);
    const float* X = th ? thermal : optical;
    unsigned short* Xb = th ? Xbt : Xbo;
    const int CIN = th ? 256 : 128;
    const int n0 = (th ? bx : bx - 64) * 64;
    const int nl = tid & 63;
    const int cw = (tid >> 6) * 4;
    for (int c0 = 0; c0 < CIN; c0 += 16) {
      int c = c0 + cw;
      float x0 = X[(size_t)(c + 0) * N_TOK + n0 + nl];
      float x1 = X[(size_t)(c + 1) * N_TOK + n0 + nl];
      float x2 = X[(size_t)(c + 2) * N_TOK + n0 + nl];
      float x3 = X[(size_t)(c + 3) * N_TOK + n0 + nl];
      uint2 w; w.x = pkbf(x0, x1); w.y = pkbf(x2, x3);
      *(uint2*)&tile[nl][c] = w;
    }
    __syncthreads();
    const int n = tid >> 2, q = tid & 3;
    const int cb = q * (CIN / 4);
    for (int j = 0; j < CIN / 4; j += 4)
      *(uint2*)(Xb + (size_t)(n0 + n) * CIN + cb + j) = *(const uint2*)&tile[n][cb + j];
  } else if (bx < 224) {
    int i = (bx - 128) * 2048 + tid * 8;   // 196608 total
    const float* src; int off;
    if (i < 65536)       { src = Wq; off = 0; }
    else if (i < 98304)  { src = Wk; off = 65536; }
    else if (i < 131072) { src = Wv; off = 98304; }
    else                 { src = Wp; off = 131072; }
    float4 f0 = *(const float4*)(src + (i - off));
    float4 f1 = *(const float4*)(src + (i - off) + 4);
    uint4 o;
    o.x = pkbf(f0.x, f0.y); o.y = pkbf(f0.z, f0.w);
    o.z = pkbf(f1.x, f1.y); o.w = pkbf(f1.z, f1.w);
    *(uint4*)(Wall + i) = o;
  } else {
    int n = (bx - 224) * 256 + tid;
    int y = n >> 6, x = n & 63;
    float e[9];
#pragma unroll
    for (int dy = 0; dy < 3; dy++)
#pragma unroll
      for (int dx = 0; dx < 3; dx++) {
        int yy = y + dy - 1, xx = x + dx - 1;
        e[dy * 3 + dx] = (yy >= 0 && yy < 64 && xx >= 0 && xx < 64)
                             ? em[yy * 64 + xx] : 0.f;
      }
    float c1[32];
#pragma unroll
    for (int oc = 0; oc < 32; oc++) {
      float a = b1[oc];
#pragma unroll
      for (int t = 0; t < 9; t++) a = fmaf(e[t], w1[oc * 9 + t], a);
      c1[oc] = fmaxf(a, 0.f);
    }
#pragma unroll
    for (int hh = 0; hh < 8; hh++) {
      float a = b2[hh];
#pragma unroll
      for (int oc = 0; oc < 32; oc++) a = fmaf(c1[oc], w2[hh * 32 + oc], a);
      g[hh * N_TOK + n] = 1.f / (1.f + __expf(-a));
    }
  }
}

// ---------------------------------------------------------------------------
// Shared 32tok x 32out MFMA tile.
// ---------------------------------------------------------------------------
template <int CIN>
__device__ __forceinline__ void gemm_tile(
    const unsigned short* __restrict__ xp, const unsigned short* __restrict__ wp,
    f32x16& accE, f32x16& accO)
{
#pragma unroll
  for (int c = 0; c < CIN; c += 32) {
    bf16x8 a0 = *(const bf16x8*)(xp + c);
    bf16x8 b0 = *(const bf16x8*)(wp + c);
    bf16x8 a1 = *(const bf16x8*)(xp + c + 16);
    bf16x8 b1 = *(const bf16x8*)(wp + c + 16);
    accE = __builtin_amdgcn_mfma_f32_32x32x16_bf16(a0, b0, accE, 0, 0, 0);
    accO = __builtin_amdgcn_mfma_f32_32x32x16_bf16(a1, b1, accO, 0, 0, 0);
  }
}

// ---------------------------------------------------------------------------
// Fused QKV projection. grid (32, 24).
// ---------------------------------------------------------------------------
__global__ __launch_bounds__(256) void qkv_kernel(
    const unsigned short* __restrict__ Xbt, const unsigned short* __restrict__ Xbo,
    const unsigned short* __restrict__ Wall,
    const float* __restrict__ bq, const float* __restrict__ bk,
    const float* __restrict__ bv, const float* __restrict__ g,
    unsigned short* __restrict__ Qh, unsigned short* __restrict__ Kh,
    unsigned short* __restrict__ Vf)
{
  __shared__ float ldsT[4][32][33];
  const int tid = threadIdx.x;
  const int wave = tid >> 6, lane = tid & 63;
  const int l31 = lane & 31, hi = lane >> 5;
  const int y = blockIdx.y;
  const int head = y & 7;
  const int n0 = blockIdx.x * 128 + wave * 32;

  f32x16 accE, accO;
#pragma unroll
  for (int i = 0; i < 16; i++) { accE[i] = 0.f; accO[i] = 0.f; }
  float bo;
  if (y < 8) {
    gemm_tile<256>(Xbt + (size_t)(n0 + l31) * 256 + hi * 8,
                   Wall + (size_t)(head * 32 + l31) * 256 + hi * 8, accE, accO);
    bo = bq[head * 32 + l31];
  } else if (y < 16) {
    gemm_tile<128>(Xbo + (size_t)(n0 + l31) * 128 + hi * 8,
                   Wall + 65536 + (size_t)(head * 32 + l31) * 128 + hi * 8, accE, accO);
    bo = bk[head * 32 + l31];
  } else {
    gemm_tile<128>(Xbo + (size_t)(n0 + l31) * 128 + hi * 8,
                   Wall + 98304 + (size_t)(head * 32 + l31) * 128 + hi * 8, accE, accO);
    bo = bv[head * 32 + l31];
  }
  float val[16];
#pragma unroll
  for (int r = 0; r < 16; r++) val[r] = accE[r] + accO[r] + bo;

  if (y < 8) {
    const float QSC = 0.17677669529663689f * 1.4426950408889634f;
#pragma unroll
    for (int r = 0; r < 16; r++) {
      int t = n0 + (r & 3) + 8 * (r >> 2) + 4 * hi;
      val[r] *= QSC * g[head * N_TOK + t];
    }
  }
#pragma unroll
  for (int r = 0; r < 16; r++)
    ldsT[wave][(r & 3) + 8 * (r >> 2) + 4 * hi][l31] = val[r];

  if (y < 16) {
    unsigned pk[8];
#pragma unroll
    for (int i = 0; i < 8; i++)
      pk[i] = pkbf(ldsT[wave][l31][16 * hi + 2 * i],
                   ldsT[wave][l31][16 * hi + 2 * i + 1]);
    unsigned short* dst = (y < 8 ? Qh : Kh) +
        ((size_t)head * N_TOK + n0 + l31) * 32 + 16 * hi;
    *(uint4*)dst = make_uint4(pk[0], pk[1], pk[2], pk[3]);
    *(uint4*)(dst + 8) = make_uint4(pk[4], pk[5], pk[6], pk[7]);
  } else {
    unsigned pk[8];
#pragma unroll
    for (int i = 0; i < 8; i++)
      pk[i] = pkbf(ldsT[wave][16 * hi + 2 * i][l31],
                   ldsT[wave][16 * hi + 2 * i + 1][l31]);
    unsigned short* dst = Vf +
        (((size_t)head * 256 + (n0 >> 4) + hi) * 32 + l31) * 16;
    *(uint4*)dst = make_uint4(pk[0], pk[1], pk[2], pk[3]);
    *(uint4*)(dst + 8) = make_uint4(pk[4], pk[5], pk[6], pk[7]);
  }
}

// ---------------------------------------------------------------------------
// Flash attention, DUAL-Q-GROUP K/V sharing. Block = 64 q-rows of one head =
// two 32-row groups sharing every K/V fragment; grid 512 (=2 blocks/CU),
// __launch_bounds__(256,2) -> 256-VGPR budget. XCD-pinned heads (bid&7),
// in-block K-split (wave = 1024 keys), setprio on MFMA clusters, 1-deep
// prefetch, bf16 Ab epilogue (two LDS combine rounds).  [R17 best: 58.4us]
// ---------------------------------------------------------------------------
__global__ __launch_bounds__(256, 2) void attn_kernel(
    const unsigned short* __restrict__ Qh, const unsigned short* __restrict__ Kh,
    const unsigned short* __restrict__ Vf, unsigned short* __restrict__ Ab)
{
  __shared__ float combA[4][32][33];
  __shared__ float combL[4][32];
  const int tid = threadIdx.x;
  const int wave = tid >> 6, lane = tid & 63;
  const int l31 = lane & 31, hi = lane >> 5;
  const int hh = blockIdx.x & 7;          // XCD-pinned head
  const int qb = blockIdx.x >> 3;         // 0..63
  const int qrow0 = qb * 64;              // group A; group B = +32
  const int kbase0 = wave * 1024;

  const unsigned short* qrowA = Qh + ((size_t)hh * N_TOK + qrow0 + l31) * 32;
  const bf16x8 qfA0 = *(const bf16x8*)(qrowA + hi * 8);
  const bf16x8 qfA1 = *(const bf16x8*)(qrowA + 16 + hi * 8);
  const unsigned short* qrowB = qrowA + 32 * 32;
  const bf16x8 qfB0 = *(const bf16x8*)(qrowB + hi * 8);
  const bf16x8 qfB1 = *(const bf16x8*)(qrowB + 16 + hi * 8);

  const unsigned short* kb_base = Kh + (size_t)hh * (N_TOK * 32);
  const unsigned short* vf_base = Vf + (size_t)hh * (256 * 32 * 16);

  f32x16 accA, accB, zero16;
#pragma unroll
  for (int i = 0; i < 16; i++) { accA[i] = 0.f; accB[i] = 0.f; zero16[i] = 0.f; }
  float lsumA = 0.f, lsumB = 0.f;

#define LK(kb, s) (*(const bf16x8*)(kb_base + (size_t)((kb) + l31) * 32 + (s) * 16 + hi * 8))
#define LV(kt2)   (*(const bf16x8*)(vf_base + (size_t)((kt2) * 32 + l31) * 16 + hi * 8))

  bf16x8 kf0 = LK(kbase0, 0), kf1 = LK(kbase0, 1);
  bf16x8 vb0 = LV(kbase0 >> 4), vb1 = LV((kbase0 >> 4) + 1);

#pragma unroll 2
  for (int kt = 0; kt < 1024; kt += 32) {
    const int nxt = (kt + 32 < 1024) ? (kbase0 + kt + 32) : kbase0;
    bf16x8 nk0 = LK(nxt, 0), nk1 = LK(nxt, 1);
    bf16x8 nv0 = LV(nxt >> 4), nv1 = LV((nxt >> 4) + 1);

    __builtin_amdgcn_s_setprio(1);
    f32x16 sA = __builtin_amdgcn_mfma_f32_32x32x16_bf16(kf0, qfA0, zero16, 0, 0, 0);
    sA = __builtin_amdgcn_mfma_f32_32x32x16_bf16(kf1, qfA1, sA, 0, 0, 0);
    f32x16 sB = __builtin_amdgcn_mfma_f32_32x32x16_bf16(kf0, qfB0, zero16, 0, 0, 0);
    sB = __builtin_amdgcn_mfma_f32_32x32x16_bf16(kf1, qfB1, sB, 0, 0, 0);
    __builtin_amdgcn_s_setprio(0);

    float pA[16], pB[16];
#pragma unroll
    for (int r = 0; r < 16; r++) pA[r] = fexp2(sA[r]);
#pragma unroll
    for (int r = 0; r < 16; r++) pB[r] = fexp2(sB[r]);

    lsumA += (((pA[0] + pA[1]) + (pA[2] + pA[3])) + ((pA[4] + pA[5]) + (pA[6] + pA[7]))) +
             (((pA[8] + pA[9]) + (pA[10] + pA[11])) + ((pA[12] + pA[13]) + (pA[14] + pA[15])));
    lsumB += (((pB[0] + pB[1]) + (pB[2] + pB[3])) + ((pB[4] + pB[5]) + (pB[6] + pB[7]))) +
             (((pB[8] + pB[9]) + (pB[10] + pB[11])) + ((pB[12] + pB[13]) + (pB[14] + pB[15])));

    unsigned aA0 = pkbf(pA[0], pA[1]),   aA1 = pkbf(pA[2], pA[3]);
    unsigned bA0 = pkbf(pA[4], pA[5]),   bA1 = pkbf(pA[6], pA[7]);
    unsigned cA0 = pkbf(pA[8], pA[9]),   cA1 = pkbf(pA[10], pA[11]);
    unsigned dA0 = pkbf(pA[12], pA[13]), dA1 = pkbf(pA[14], pA[15]);
    asm("v_permlane32_swap_b32 %0, %1" : "+v"(aA0), "+v"(bA0));
    asm("v_permlane32_swap_b32 %0, %1" : "+v"(aA1), "+v"(bA1));
    asm("v_permlane32_swap_b32 %0, %1" : "+v"(cA0), "+v"(dA0));
    asm("v_permlane32_swap_b32 %0, %1" : "+v"(cA1), "+v"(dA1));
    unsigned aB0 = pkbf(pB[0], pB[1]),   aB1 = pkbf(pB[2], pB[3]);
    unsigned bB0 = pkbf(pB[4], pB[5]),   bB1 = pkbf(pB[6], pB[7]);
    unsigned cB0 = pkbf(pB[8], pB[9]),   cB1 = pkbf(pB[10], pB[11]);
    unsigned dB0 = pkbf(pB[12], pB[13]), dB1 = pkbf(pB[14], pB[15]);
    asm("v_permlane32_swap_b32 %0, %1" : "+v"(aB0), "+v"(bB0));
    asm("v_permlane32_swap_b32 %0, %1" : "+v"(aB1), "+v"(bB1));
    asm("v_permlane32_swap_b32 %0, %1" : "+v"(cB0), "+v"(dB0));
    asm("v_permlane32_swap_b32 %0, %1" : "+v"(cB1), "+v"(dB1));
    union { unsigned w[4]; bf16x8 v; } uA0, uA1, uB0, uB1;
    uA0.w[0] = aA0; uA0.w[1] = aA1; uA0.w[2] = bA0; uA0.w[3] = bA1;
    uA1.w[0] = cA0; uA1.w[1] = cA1; uA1.w[2] = dA0; uA1.w[3] = dA1;
    uB0.w[0] = aB0; uB0.w[1] = aB1; uB0.w[2] = bB0; uB0.w[3] = bB1;
    uB1.w[0] = cB0; uB1.w[1] = cB1; uB1.w[2] = dB0; uB1.w[3] = dB1;

    __builtin_amdgcn_s_setprio(1);
    accA = __builtin_amdgcn_mfma_f32_32x32x16_bf16(uA0.v, vb0, accA, 0, 0, 0);
    accA = __builtin_amdgcn_mfma_f32_32x32x16_bf16(uA1.v, vb1, accA, 0, 0, 0);
    accB = __builtin_amdgcn_mfma_f32_32x32x16_bf16(uB0.v, vb0, accB, 0, 0, 0);
    accB = __builtin_amdgcn_mfma_f32_32x32x16_bf16(uB1.v, vb1, accB, 0, 0, 0);
    __builtin_amdgcn_s_setprio(0);

    kf0 = nk0; kf1 = nk1; vb0 = nv0; vb1 = nv1;
  }
#undef LK
#undef LV

  const int t = tid >> 3;                  // token 0..31
  const int c4 = (tid & 7) * 4;            // vch group

  // ---- group A combine ----
  float ltA = lsumA + __shfl_xor(lsumA, 32);
  if (hi == 0) combL[wave][l31] = ltA;
#pragma unroll
  for (int r = 0; r < 16; r++)
    combA[wave][(r & 3) + 8 * (r >> 2) + 4 * hi][l31] = accA[r];
  __syncthreads();
  {
    float l = combL[0][t] + combL[1][t] + combL[2][t] + combL[3][t];
    float inv = 1.f / l;
    float o[4];
#pragma unroll
    for (int j = 0; j < 4; j++)
      o[j] = combA[0][t][c4 + j] + combA[1][t][c4 + j] +
             combA[2][t][c4 + j] + combA[3][t][c4 + j];
    uint2 pk;
    pk.x = pkbf(o[0] * inv, o[1] * inv);
    pk.y = pkbf(o[2] * inv, o[3] * inv);
    *(uint2*)(Ab + (size_t)(qrow0 + t) * CT + hh * 32 + c4) = pk;
  }
  __syncthreads();

  // ---- group B combine ----
  float ltB = lsumB + __shfl_xor(lsumB, 32);
  if (hi == 0) combL[wave][l31] = ltB;
#pragma unroll
  for (int r = 0; r < 16; r++)
    combA[wave][(r & 3) + 8 * (r >> 2) + 4 * hi][l31] = accB[r];
  __syncthreads();
  {
    float l = combL[0][t] + combL[1][t] + combL[2][t] + combL[3][t];
    float inv = 1.f / l;
    float o[4];
#pragma unroll
    for (int j = 0; j < 4; j++)
      o[j] = combA[0][t][c4 + j] + combA[1][t][c4 + j] +
             combA[2][t][c4 + j] + combA[3][t][c4 + j];
    uint2 pk;
    pk.x = pkbf(o[0] * inv, o[1] * inv);
    pk.y = pkbf(o[2] * inv, o[3] * inv);
    *(uint2*)(Ab + (size_t)(qrow0 + 32 + t) * CT + hh * 32 + c4) = pk;
  }
}

// ---------------------------------------------------------------------------
// Output projection, 4-wave CIN-split. grid (128, 8).
// ---------------------------------------------------------------------------
__global__ __launch_bounds__(256, 4) void pout_kernel(
    const unsigned short* __restrict__ Ab, const unsigned short* __restrict__ Wall,
    const float* __restrict__ bp, float* __restrict__ out)
{
  __shared__ float comb[4][32][33];
  const int tid = threadIdx.x;
  const int wave = tid >> 6, lane = tid & 63;
  const int l31 = lane & 31, hi = lane >> 5;
  const int n0 = blockIdx.x * 32;
  const int o0 = blockIdx.y * 32;
  const int cbase = wave * 64;

  const unsigned short* xp = Ab + (size_t)(n0 + l31) * 256 + cbase + hi * 8;
  const unsigned short* wp = Wall + 131072 + (size_t)(o0 + l31) * 256 + cbase + hi * 8;

  f32x16 accE, accO;
#pragma unroll
  for (int i = 0; i < 16; i++) { accE[i] = 0.f; accO[i] = 0.f; }
#pragma unroll
  for (int c = 0; c < 64; c += 32) {
    bf16x8 a0 = *(const bf16x8*)(xp + c);
    bf16x8 b0 = *(const bf16x8*)(wp + c);
    bf16x8 a1 = *(const bf16x8*)(xp + c + 16);
    bf16x8 b1 = *(const bf16x8*)(wp + c + 16);
    accE = __builtin_amdgcn_mfma_f32_32x32x16_bf16(a0, b0, accE, 0, 0, 0);
    accO = __builtin_amdgcn_mfma_f32_32x32x16_bf16(a1, b1, accO, 0, 0, 0);
  }
#pragma unroll
  for (int r = 0; r < 16; r++)
    comb[wave][(r & 3) + 8 * (r >> 2) + 4 * hi][l31] = accE[r] + accO[r];
  __syncthreads();

  const int oc = tid >> 3;                 // 0..31
  const int t4 = (tid & 7) * 4;            // 0..28
  const float bo = bp[o0 + oc];
  float4 w;
  w.x = comb[0][t4 + 0][oc] + comb[1][t4 + 0][oc] + comb[2][t4 + 0][oc] + comb[3][t4 + 0][oc] + bo;
  w.y = comb[0][t4 + 1][oc] + comb[1][t4 + 1][oc] + comb[2][t4 + 1][oc] + comb[3][t4 + 1][oc] + bo;
  w.z = comb[0][t4 + 2][oc] + comb[1][t4 + 2][oc] + comb[2][t4 + 2][oc] + comb[3][t4 + 2][oc] + bo;
  w.w = comb[0][t4 + 3][oc] + comb[1][t4 + 3][oc] + comb[2][t4 + 3][oc] + comb[3][t4 + 3][oc] + bo;
  *(float4*)(out + (size_t)(o0 + oc) * N_TOK + n0 + t4) = w;
}

// ---------------------------------------------------------------------------
extern "C" void kernel_launch(void* const* d_in, const int* in_sizes, int n_in,
                              void* d_out, int out_size, void* d_ws, size_t ws_size,
                              hipStream_t stream)
{
  const float* thermal = (const float*)d_in[0];
  const float* optical = (const float*)d_in[1];
  const float* em      = (const float*)d_in[2];
  const float* Wq = (const float*)d_in[3];
  const float* bq = (const float*)d_in[4];
  const float* Wk = (const float*)d_in[5];
  const float* bk = (const float*)d_in[6];
  const float* Wv = (const float*)d_in[7];
  const float* bv = (const float*)d_in[8];
  const float* w1 = (const float*)d_in[9];
  const float* b1 = (const float*)d_in[10];
  const float* w2 = (const float*)d_in[11];
  const float* b2 = (const float*)d_in[12];
  const float* Wp = (const float*)d_in[13];
  const float* bp = (const float*)d_in[14];

  char* ws = (char*)d_ws;
  const size_t MB = 1u << 20;
  unsigned short* Xbt = (unsigned short*)(ws);                  // 2MB
  unsigned short* Xbo = (unsigned short*)(ws + 2 * MB);         // 1MB
  unsigned short* Wall = (unsigned short*)(ws + 3 * MB);        // 384KB
  float* gbuf = (float*)(ws + 3 * MB + 512 * 1024);             // 128KB
  unsigned short* Qh = (unsigned short*)(ws + 4 * MB);          // 2MB
  unsigned short* Kh = (unsigned short*)(ws + 6 * MB);          // 2MB
  unsigned short* Vf = (unsigned short*)(ws + 8 * MB);          // 2MB
  unsigned short* Ab = (unsigned short*)(ws + 10 * MB);         // 2MB

  prep_kernel<<<240, 256, 0, stream>>>(thermal, optical, Wq, Wk, Wv, Wp,
                                       em, w1, b1, w2, b2, Xbt, Xbo, Wall, gbuf);
  qkv_kernel<<<dim3(32, 24), 256, 0, stream>>>(Xbt, Xbo, Wall, bq, bk, bv, gbuf,
                                               Qh, Kh, Vf);
  attn_kernel<<<512, 256, 0, stream>>>(Qh, Kh, Vf, Ab);
  pout_kernel<<<dim3(128, 8), 256, 0, stream>>>(Ab, Wall, bp, (float*)d_out);
}